// Round 1
// baseline (900.013 us; speedup 1.0000x reference)
//
#include <hip/hip_runtime.h>

// Child-Sum Tree-LSTM fused kernel, MI355X/gfx950 — v2.
// v1 diagnosis: latency-bound (MfmaUtil 16%, VALU 29.6%, HBM 15.7%). This round:
//  (1) 3-buffer LDS pipeline: read -> write-next -> ONE sync per child (was 2),
//      h_{k+1} prefetched into regs across the MFMA section.
//  (2) split cost ~halved: RNE-hi + trunc-lo packed via v_perm_b32.
//  (3) fast-divide sigmoid/tanh; batched c_child loads; s_setprio around MFMA.
//  (4) __launch_bounds__(256,3): VGPR cap 170, 3 blocks/CU (LDS 52.2 KB).

#define NN 131072          // nodes
#define LDSS 136           // LDS row stride in bf16 elems (128 + 8 pad)

typedef __attribute__((ext_vector_type(8))) short bf16x8;
typedef __attribute__((ext_vector_type(4))) float f32x4;

// d_ws layout, in ushort (bf16) units. Weights pre-split + pre-swizzled to MFMA-B fragment order.
#define BX_HI 0            // [W_iou | W_f] : 128 x 512
#define BX_LO 65536
#define BH_HI 131072       // U_iou : 128 x 384
#define BH_LO 180224
#define UF_HI 229376       // U_f : 128 x 128
#define UF_LO 245760

__device__ __forceinline__ unsigned short f2bf(float f){
  unsigned int u = __float_as_uint(f);
  u += 0x7FFFu + ((u >> 16) & 1u);   // round-to-nearest-even
  return (unsigned short)(u >> 16);
}
__device__ __forceinline__ float bf2f(unsigned short h){
  return __uint_as_float(((unsigned int)h) << 16);
}
__device__ __forceinline__ float sigm(float v){
  return __fdividef(1.f, 1.f + __expf(-v));
}
__device__ __forceinline__ float tanh_f(float v){
  float a = fabsf(v);
  float e = __expf(-2.f * a);
  float r = __fdividef(1.f - e, 1.f + e);
  return copysignf(r, v);
}

__device__ __forceinline__ void load8(float* v, const float* p){
  float4 a = ((const float4*)p)[0];
  float4 b = ((const float4*)p)[1];
  v[0]=a.x; v[1]=a.y; v[2]=a.z; v[3]=a.w;
  v[4]=b.x; v[5]=b.y; v[6]=b.z; v[7]=b.w;
}

// Split 8 floats into hi/lo bf16 and store 16B each to LDS.
// hi = RNE bf16 (same as v1); lo = (f - hi) truncated to bf16 (error ~2^-17 |f|, unchanged order).
// Packing via v_perm_b32: bytes [3:2] of each rounded word -> ~6 VALU/elem vs ~10.
__device__ __forceinline__ void split8_store(unsigned short* hp, unsigned short* lp,
                                             const float* v){
  unsigned int r[8]; unsigned int lo[8];
#pragma unroll
  for (int i = 0; i < 8; ++i){
    unsigned int u = __float_as_uint(v[i]);
    r[i] = u + (0x7FFFu + ((u >> 16) & 1u));
    lo[i] = __float_as_uint(v[i] - __uint_as_float(r[i] & 0xFFFF0000u));
  }
  uint4 uh, ul;
  uh.x = __builtin_amdgcn_perm(r[1], r[0], 0x07060302u);
  uh.y = __builtin_amdgcn_perm(r[3], r[2], 0x07060302u);
  uh.z = __builtin_amdgcn_perm(r[5], r[4], 0x07060302u);
  uh.w = __builtin_amdgcn_perm(r[7], r[6], 0x07060302u);
  ul.x = __builtin_amdgcn_perm(lo[1], lo[0], 0x07060302u);
  ul.y = __builtin_amdgcn_perm(lo[3], lo[2], 0x07060302u);
  ul.z = __builtin_amdgcn_perm(lo[5], lo[4], 0x07060302u);
  ul.w = __builtin_amdgcn_perm(lo[7], lo[6], 0x07060302u);
  *(uint4*)hp = uh;
  *(uint4*)lp = ul;
}

// ---- prep: split weights to hi/lo bf16, swizzled into MFMA-B fragment order (unchanged, verified) ----
__global__ void prep_weights(const float* __restrict__ Wiou, const float* __restrict__ Uiou,
                             const float* __restrict__ Wf, const float* __restrict__ Uf,
                             unsigned short* __restrict__ ws){
  int tid = blockIdx.x * 256 + threadIdx.x;  // 0 .. 131071
  float v; int k, col, nt; unsigned int bhi, blo;
  if (tid < 65536){                       // Bx: 128 x 512 = [W_iou | W_f]
    k = tid >> 9; col = tid & 511;
    v = (col < 384) ? Wiou[k * 384 + col] : Wf[k * 128 + (col - 384)];
    nt = 32; bhi = BX_HI; blo = BX_LO;
  } else if (tid < 65536 + 49152){        // Bh: 128 x 384 = U_iou
    int s = tid - 65536; k = s / 384; col = s - k * 384;
    v = Uiou[k * 384 + col];
    nt = 24; bhi = BH_HI; blo = BH_LO;
  } else {                                // Uf: 128 x 128
    int s = tid - 65536 - 49152; k = s >> 7; col = s & 127;
    v = Uf[k * 128 + col];
    nt = 8; bhi = UF_HI; blo = UF_LO;
  }
  int kc = k >> 5, q = (k >> 3) & 3, j = k & 7;
  int nc = col >> 4, cc = col & 15;
  int lane = q * 16 + cc;
  unsigned int addr = ((unsigned)(kc * nt + nc) * 64u + (unsigned)lane) * 8u + (unsigned)j;
  unsigned short hi = f2bf(v);
  unsigned short lo = f2bf(v - bf2f(hi));
  ws[bhi + addr] = hi;
  ws[blo + addr] = lo;
}

// ---- main fused kernel ----
// block = 256 threads (4 waves), M = 32 nodes/block. Wave w owns features [32w, 32w+32).
// LDS: X tile (x) + H0/H1 ping-pong (h_child / h_sum). 5 barriers/block total.
__launch_bounds__(256, 3)
__global__ void tree_lstm_fused(const float* __restrict__ xg,
                                const float* __restrict__ hcg,
                                const float* __restrict__ ccg,
                                const float* __restrict__ b_iou,
                                const float* __restrict__ b_f,
                                const unsigned short* __restrict__ ws,
                                float* __restrict__ out){
  __shared__ alignas(16) unsigned short AxHi[32 * LDSS];
  __shared__ alignas(16) unsigned short AxLo[32 * LDSS];
  __shared__ alignas(16) unsigned short H0Hi[32 * LDSS];
  __shared__ alignas(16) unsigned short H0Lo[32 * LDSS];
  __shared__ alignas(16) unsigned short H1Hi[32 * LDSS];
  __shared__ alignas(16) unsigned short H1Lo[32 * LDSS];

  const int t = threadIdx.x;
  const int lane = t & 63;
  const int w = t >> 6;          // wave 0..3
  const int m = lane & 15;       // A-frag row / C col (feature)
  const int q = lane >> 4;       // quad
  const int node0 = blockIdx.x * 32;
  const int nc0 = 2 * w;
  const int row0 = t >> 4;       // 0..15 (staging row, group 0)
  const int col8 = t & 15;
  const int row1 = row0 + 16;    // 16..31 (staging row, group 1)

  // ---- entry: load x tile and h_child[0] tile, split both to LDS ----
  float xv0[8], xv1[8], hv0[8], hv1[8];
  load8(xv0, xg + (size_t)(node0 + row0) * 128 + col8 * 8);
  load8(xv1, xg + (size_t)(node0 + row1) * 128 + col8 * 8);
  load8(hv0, hcg + ((size_t)(node0 + row0) * 4 + 0) * 128 + col8 * 8);
  load8(hv1, hcg + ((size_t)(node0 + row1) * 4 + 0) * 128 + col8 * 8);

  split8_store(AxHi + row0 * LDSS + col8 * 8, AxLo + row0 * LDSS + col8 * 8, xv0);
  split8_store(AxHi + row1 * LDSS + col8 * 8, AxLo + row1 * LDSS + col8 * 8, xv1);
  split8_store(H0Hi + row0 * LDSS + col8 * 8, H0Lo + row0 * LDSS + col8 * 8, hv0);
  split8_store(H0Hi + row1 * LDSS + col8 * 8, H0Lo + row1 * LDSS + col8 * 8, hv1);

  float hs0[8], hs1[8];
#pragma unroll
  for (int i = 0; i < 8; ++i){ hs0[i] = hv0[i]; hs1[i] = hv1[i]; }

  float bfv[2];
#pragma unroll
  for (int ct = 0; ct < 2; ++ct) bfv[ct] = b_f[w * 32 + ct * 16 + m];

  __syncthreads();   // sync #1: X and H0 ready

  // prefetch h_child[1] during GEMM1 (consumed in k=0's write phase)
  load8(hv0, hcg + ((size_t)(node0 + row0) * 4 + 1) * 128 + col8 * 8);
  load8(hv1, hcg + ((size_t)(node0 + row1) * 4 + 1) * 128 + col8 * 8);

  // ---- GEMM1: x @ [W_iou | W_f] ----
  const f32x4 zero = {0.f, 0.f, 0.f, 0.f};
  f32x4 acc[8][2];
#pragma unroll
  for (int c = 0; c < 8; ++c)
#pragma unroll
    for (int rt = 0; rt < 2; ++rt) acc[c][rt] = zero;
  f32x4 fc[2][2];
#pragma unroll
  for (int ct = 0; ct < 2; ++ct)
#pragma unroll
    for (int rt = 0; rt < 2; ++rt) fc[ct][rt] = zero;

  __builtin_amdgcn_s_setprio(1);
#pragma unroll
  for (int kc = 0; kc < 4; ++kc){
    bf16x8 ah[2], al[2];
#pragma unroll
    for (int rt = 0; rt < 2; ++rt){
      int off = (rt * 16 + m) * LDSS + kc * 32 + q * 8;
      ah[rt] = *(const bf16x8*)(AxHi + off);
      al[rt] = *(const bf16x8*)(AxLo + off);
    }
#pragma unroll
    for (int c = 0; c < 8; ++c){
      int nc = (c >> 1) * 8 + nc0 + (c & 1);
      bf16x8 bh = *(const bf16x8*)(ws + BX_HI + ((kc * 32 + nc) * 64 + lane) * 8);
      bf16x8 bl = *(const bf16x8*)(ws + BX_LO + ((kc * 32 + nc) * 64 + lane) * 8);
#pragma unroll
      for (int rt = 0; rt < 2; ++rt){
        acc[c][rt] = __builtin_amdgcn_mfma_f32_16x16x32_bf16(ah[rt], bh, acc[c][rt], 0, 0, 0);
        acc[c][rt] = __builtin_amdgcn_mfma_f32_16x16x32_bf16(al[rt], bh, acc[c][rt], 0, 0, 0);
        acc[c][rt] = __builtin_amdgcn_mfma_f32_16x16x32_bf16(ah[rt], bl, acc[c][rt], 0, 0, 0);
      }
    }
  }
  __builtin_amdgcn_s_setprio(0);

  // ---- children loop: read H[k&1], write h_{k+1} (or h_sum) to H[(k+1)&1], ONE sync ----
#pragma unroll
  for (int k = 0; k < 4; ++k){
    const unsigned short* HHi = (k & 1) ? H1Hi : H0Hi;
    const unsigned short* HLo = (k & 1) ? H1Lo : H0Lo;

    f32x4 hu[2][2];
#pragma unroll
    for (int ct = 0; ct < 2; ++ct)
#pragma unroll
      for (int rt = 0; rt < 2; ++rt) hu[ct][rt] = zero;

    __builtin_amdgcn_s_setprio(1);
#pragma unroll
    for (int kc = 0; kc < 4; ++kc){
      bf16x8 ah[2], al[2];
#pragma unroll
      for (int rt = 0; rt < 2; ++rt){
        int off = (rt * 16 + m) * LDSS + kc * 32 + q * 8;
        ah[rt] = *(const bf16x8*)(HHi + off);
        al[rt] = *(const bf16x8*)(HLo + off);
      }
#pragma unroll
      for (int ct = 0; ct < 2; ++ct){
        int nc = nc0 + ct;
        bf16x8 bh = *(const bf16x8*)(ws + UF_HI + ((kc * 8 + nc) * 64 + lane) * 8);
        bf16x8 bl = *(const bf16x8*)(ws + UF_LO + ((kc * 8 + nc) * 64 + lane) * 8);
#pragma unroll
        for (int rt = 0; rt < 2; ++rt){
          hu[ct][rt] = __builtin_amdgcn_mfma_f32_16x16x32_bf16(ah[rt], bh, hu[ct][rt], 0, 0, 0);
          hu[ct][rt] = __builtin_amdgcn_mfma_f32_16x16x32_bf16(al[rt], bh, hu[ct][rt], 0, 0, 0);
          hu[ct][rt] = __builtin_amdgcn_mfma_f32_16x16x32_bf16(ah[rt], bl, hu[ct][rt], 0, 0, 0);
        }
      }
    }
    __builtin_amdgcn_s_setprio(0);

    // batched c_child loads, then fused forget-gate epilogue
    float cv[2][2][4];
#pragma unroll
    for (int ct = 0; ct < 2; ++ct)
#pragma unroll
      for (int rt = 0; rt < 2; ++rt)
#pragma unroll
        for (int r = 0; r < 4; ++r)
          cv[ct][rt][r] = ccg[((size_t)(node0 + rt * 16 + q * 4 + r) * 4 + k) * 128
                              + w * 32 + ct * 16 + m];
#pragma unroll
    for (int ct = 0; ct < 2; ++ct)
#pragma unroll
      for (int rt = 0; rt < 2; ++rt)
#pragma unroll
        for (int r = 0; r < 4; ++r){
          float pre = acc[6 + ct][rt][r] + hu[ct][rt][r] + bfv[ct];
          fc[ct][rt][r] += sigm(pre) * cv[ct][rt][r];
        }

    // write phase: h_{k+1} (prefetched) or, at k==3, the accumulated h_sum
    unsigned short* WHi = ((k + 1) & 1) ? H1Hi : H0Hi;
    unsigned short* WLo = ((k + 1) & 1) ? H1Lo : H0Lo;
    if (k < 3){
      split8_store(WHi + row0 * LDSS + col8 * 8, WLo + row0 * LDSS + col8 * 8, hv0);
      split8_store(WHi + row1 * LDSS + col8 * 8, WLo + row1 * LDSS + col8 * 8, hv1);
#pragma unroll
      for (int i = 0; i < 8; ++i){ hs0[i] += hv0[i]; hs1[i] += hv1[i]; }
      if (k < 2){
        load8(hv0, hcg + ((size_t)(node0 + row0) * 4 + (k + 2)) * 128 + col8 * 8);
        load8(hv1, hcg + ((size_t)(node0 + row1) * 4 + (k + 2)) * 128 + col8 * 8);
      }
    } else {
      split8_store(WHi + row0 * LDSS + col8 * 8, WLo + row0 * LDSS + col8 * 8, hs0);
      split8_store(WHi + row1 * LDSS + col8 * 8, WLo + row1 * LDSS + col8 * 8, hs1);
    }
    __syncthreads();   // syncs #2..#5
  }

  // ---- GEMM3: h_sum @ U_iou (h_sum sits in H0 after the k==3 write) ----
  __builtin_amdgcn_s_setprio(1);
#pragma unroll
  for (int kc = 0; kc < 4; ++kc){
    bf16x8 ah[2], al[2];
#pragma unroll
    for (int rt = 0; rt < 2; ++rt){
      int off = (rt * 16 + m) * LDSS + kc * 32 + q * 8;
      ah[rt] = *(const bf16x8*)(H0Hi + off);
      al[rt] = *(const bf16x8*)(H0Lo + off);
    }
#pragma unroll
    for (int c = 0; c < 6; ++c){
      int nc = (c >> 1) * 8 + nc0 + (c & 1);
      bf16x8 bh = *(const bf16x8*)(ws + BH_HI + ((kc * 24 + nc) * 64 + lane) * 8);
      bf16x8 bl = *(const bf16x8*)(ws + BH_LO + ((kc * 24 + nc) * 64 + lane) * 8);
#pragma unroll
      for (int rt = 0; rt < 2; ++rt){
        acc[c][rt] = __builtin_amdgcn_mfma_f32_16x16x32_bf16(ah[rt], bh, acc[c][rt], 0, 0, 0);
        acc[c][rt] = __builtin_amdgcn_mfma_f32_16x16x32_bf16(al[rt], bh, acc[c][rt], 0, 0, 0);
        acc[c][rt] = __builtin_amdgcn_mfma_f32_16x16x32_bf16(ah[rt], bl, acc[c][rt], 0, 0, 0);
      }
    }
  }
  __builtin_amdgcn_s_setprio(0);

  // ---- final epilogue: gates + store h, c ----
  float biv[2], bov[2], buv[2];
#pragma unroll
  for (int ct = 0; ct < 2; ++ct){
    int f = w * 32 + ct * 16 + m;
    biv[ct] = b_iou[f];
    bov[ct] = b_iou[128 + f];
    buv[ct] = b_iou[256 + f];
  }
#pragma unroll
  for (int ct = 0; ct < 2; ++ct){
    int f = w * 32 + ct * 16 + m;
#pragma unroll
    for (int rt = 0; rt < 2; ++rt){
#pragma unroll
      for (int r = 0; r < 4; ++r){
        int node = node0 + rt * 16 + q * 4 + r;
        float iv = sigm(acc[ct][rt][r] + biv[ct]);
        float ov = sigm(acc[2 + ct][rt][r] + bov[ct]);
        float uv = tanh_f(acc[4 + ct][rt][r] + buv[ct]);
        float cvv = iv * uv + fc[ct][rt][r];
        float hvv = ov * tanh_f(cvv);
        out[(size_t)node * 128 + f] = hvv;
        out[(size_t)NN * 128 + (size_t)node * 128 + f] = cvv;
      }
    }
  }
}

extern "C" void kernel_launch(void* const* d_in, const int* in_sizes, int n_in,
                              void* d_out, int out_size, void* d_ws, size_t ws_size,
                              hipStream_t stream){
  const float* x       = (const float*)d_in[0];
  const float* h_child = (const float*)d_in[1];
  const float* c_child = (const float*)d_in[2];
  const float* W_iou   = (const float*)d_in[3];
  const float* U_iou   = (const float*)d_in[4];
  const float* b_iou   = (const float*)d_in[5];
  const float* W_f     = (const float*)d_in[6];
  const float* U_f     = (const float*)d_in[7];
  const float* b_f     = (const float*)d_in[8];
  unsigned short* ws   = (unsigned short*)d_ws;
  float* out           = (float*)d_out;

  prep_weights<<<512, 256, 0, stream>>>(W_iou, U_iou, W_f, U_f, ws);
  tree_lstm_fused<<<NN / 32, 256, 0, stream>>>(x, h_child, c_child, b_iou, b_f, ws, out);
}